// Round 6
// baseline (116.165 us; speedup 1.0000x reference)
//
#include <hip/hip_runtime.h>

#define BATCH 8
#define NROW  2048
#define NF    64
#define JSPLIT 4
#define JPB   (NROW / JSPLIT)               // 512 k per wave (split path)
#define CHUNK 32
#define TOT   ((size_t)BATCH * NROW * NF)   // 1048576

typedef float  f32x4  __attribute__((ext_vector_type(4)));
typedef __bf16 bf16x8 __attribute__((ext_vector_type(8)));
typedef unsigned short u16x8 __attribute__((ext_vector_type(8)));

union frag_cast { u16x8 u; bf16x8 b; };

__device__ __forceinline__ float ubits(unsigned u) {
  union { unsigned u; float f; } c; c.u = u; return c.f;
}
__device__ __forceinline__ unsigned fbits(float f) {
  union { float f; unsigned u; } c; c.f = f; return c.u;
}

// ---- pass 1: transpose x and split into 3 bf16 levels: xs[lvl][b][f][j] ----
// x = up(x0)+up(x1)+up(x2); x0,x1 truncation splits (exact), x2 RNE. (proven r5)
__global__ __launch_bounds__(256, 4)
void prep_x(const float* __restrict__ xg, unsigned short* __restrict__ xs) {
  __shared__ float t[64][65];
  const int b  = blockIdx.y;
  const int j0 = blockIdx.x * 64;
  const int l  = threadIdx.x & 63;
  const int g  = threadIdx.x >> 6;
  const float* src = xg + ((size_t)b * NROW + j0) * NF;
#pragma unroll
  for (int k = 0; k < 16; ++k) {
    const int j = g * 16 + k;
    t[j][l] = src[(size_t)j * NF + l];
  }
  __syncthreads();
#pragma unroll
  for (int k = 0; k < 16; ++k) {
    const int f = g * 16 + k;
    const float v = t[l][f];
    const unsigned u0 = fbits(v);
    const float f0 = ubits(u0 & 0xFFFF0000u);
    const float r  = v - f0;
    const unsigned u1 = fbits(r);
    const float f1 = ubits(u1 & 0xFFFF0000u);
    const float r2 = r - f1;
    const unsigned u2 = fbits(r2);
    const unsigned short s2 =
        (unsigned short)((u2 + 0x7FFFu + ((u2 >> 16) & 1u)) >> 16);
    const size_t o = ((size_t)b * NF + f) * NROW + j0 + l;
    xs[o]           = (unsigned short)(u0 >> 16);
    xs[o + TOT]     = (unsigned short)(u1 >> 16);
    xs[o + 2 * TOT] = s2;
  }
}

// split 8 f32 -> 3 bf16 fragments (proven r5)
__device__ __forceinline__ void split8(const f32x4 q0, const f32x4 q1,
                                       frag_cast* Af) {
  float av[8];
  *(f32x4*)&av[0] = q0;
  *(f32x4*)&av[4] = q1;
  u16x8 h0, h1, h2;
#pragma unroll
  for (int e = 0; e < 8; ++e) {
    const unsigned u0 = fbits(av[e]);
    const float f0 = ubits(u0 & 0xFFFF0000u);
    const float r  = av[e] - f0;
    const unsigned u1 = fbits(r);
    const float f1 = ubits(u1 & 0xFFFF0000u);
    const float r2 = r - f1;
    const unsigned u2 = fbits(r2);
    h0[e] = (unsigned short)(u0 >> 16);
    h1[e] = (unsigned short)(u1 >> 16);
    h2[e] = (unsigned short)((u2 + 0x7FFFu + ((u2 >> 16) & 1u)) >> 16);
  }
  Af[0].u = h0; Af[1].u = h1; Af[2].u = h2;
}

// ---- pass 2: barrier-free split-bf16 MFMA GEMM ----
// Wave = 16 rows x 64 cols x K=JPB. A loaded global->VGPR directly (lane ln:
// row ln&15, k (ln>>4)*8..+8 == MFMA A-frag layout), ping-pong prefetch 1
// chunk ahead. B-frags direct from L2-resident xs, 2 n-tiles per phase.
// No LDS, no __syncthreads. f64 master fold per chunk (proven accuracy).
template <bool DIRECT>
__global__ __launch_bounds__(256, 4)
void gemm_mfma(const float* __restrict__ ag, const unsigned short* __restrict__ xs,
               float* __restrict__ outg, float* __restrict__ wp) {
  constexpr int nch = (DIRECT ? NROW : JPB) / CHUNK;   // 64 or 16 (even)
  const int tid  = threadIdx.x;
  const int ln   = tid & 63;
  const int wv   = tid >> 6;
  const int ln15 = ln & 15;          // A row / B col / D col
  const int g    = ln >> 4;          // k-group (A/B) / D row-group
  const int b    = blockIdx.z;
  const int z    = DIRECT ? 0 : blockIdx.y;
  const int i0   = blockIdx.x * 64 + wv * 16;   // wave's first row
  const int jb   = z * JPB;

  const float* aW =
      ag + ((size_t)b * NROW + i0 + ln15) * NROW + jb + g * 8;
  const unsigned short* xb =
      xs + ((size_t)b * NF + ln15) * NROW + jb + g * 8;

  double macc[4][4];
#pragma unroll
  for (int i = 0; i < 4; ++i)
#pragma unroll
    for (int j = 0; j < 4; ++j) macc[i][j] = 0.0;

  f32x4 Aa[2], Ab[2];
  Aa[0] = *(const f32x4*)(aW);
  Aa[1] = *(const f32x4*)(aW + 4);

  auto step = [&](int t, f32x4* Ac, f32x4* An) {
    // prefetch next A chunk (HBM) before anything else
    if (t + 1 < nch) {
      An[0] = *(const f32x4*)(aW + (t + 1) * CHUNK);
      An[1] = *(const f32x4*)(aW + (t + 1) * CHUNK + 4);
    }
    frag_cast Af[3];
    split8(Ac[0], Ac[1], Af);

    f32x4 c[4];
#pragma unroll
    for (int nt = 0; nt < 4; ++nt) c[nt] = (f32x4){0.f, 0.f, 0.f, 0.f};

    constexpr int AI[6] = {2, 0, 1, 1, 0, 0};
    constexpr int BI[6] = {0, 2, 1, 0, 1, 0};

#pragma unroll
    for (int ng = 0; ng < 2; ++ng) {
      frag_cast Bv[2][3];
#pragma unroll
      for (int nn = 0; nn < 2; ++nn)
#pragma unroll
        for (int lvl = 0; lvl < 3; ++lvl)
          Bv[nn][lvl].u = *(const u16x8*)(
              xb + (size_t)(ng * 2 + nn) * 16 * NROW + (size_t)lvl * TOT +
              (size_t)t * CHUNK);
      // 6 split-terms (ascending magnitude), 2 independent chains interleaved
#pragma unroll
      for (int term = 0; term < 6; ++term)
#pragma unroll
        for (int nn = 0; nn < 2; ++nn) {
          const int nt = ng * 2 + nn;
          c[nt] = __builtin_amdgcn_mfma_f32_16x16x32_bf16(
              Af[AI[term]].b, Bv[nn][BI[term]].b, c[nt], 0, 0, 0);
        }
    }
    // fold chunk sums into f64 masters
#pragma unroll
    for (int nt = 0; nt < 4; ++nt) {
      macc[nt][0] += (double)c[nt].x;
      macc[nt][1] += (double)c[nt].y;
      macc[nt][2] += (double)c[nt].z;
      macc[nt][3] += (double)c[nt].w;
    }
  };

#pragma unroll 1
  for (int t = 0; t < nch; t += 2) {
    step(t, Aa, Ab);
    step(t + 1, Ab, Aa);
  }

  // epilogue: D row = g*4 + r, col = nt*16 + ln15 (verified layout)
  if (DIRECT) {
#pragma unroll
    for (int nt = 0; nt < 4; ++nt)
#pragma unroll
      for (int r = 0; r < 4; ++r)
        outg[((size_t)b * NROW + i0 + g * 4 + r) * NF + nt * 16 + ln15] =
            (macc[nt][r] > 0.5) ? 1.0f : 0.0f;
  } else {
    float* wb = wp + (size_t)z * TOT;
#pragma unroll
    for (int nt = 0; nt < 4; ++nt)
#pragma unroll
      for (int r = 0; r < 4; ++r)
        wb[((size_t)b * NROW + i0 + g * 4 + r) * NF + nt * 16 + ln15] =
            (float)macc[nt][r];
  }
}

// ---- pass 3: reduce JSPLIT partials in f64, threshold ----
__global__ __launch_bounds__(256)
void combine_thresh(const float* __restrict__ wsv, float* __restrict__ outg) {
  const size_t e = ((size_t)blockIdx.x * 256 + threadIdx.x) * 4;
  f32x4 p0 = *(const f32x4*)(wsv + e);
  f32x4 p1 = *(const f32x4*)(wsv + e + TOT);
  f32x4 p2 = *(const f32x4*)(wsv + e + 2 * TOT);
  f32x4 p3 = *(const f32x4*)(wsv + e + 3 * TOT);
  f32x4 o;
  o.x = (((double)p0.x + p1.x + p2.x + p3.x) > 0.5) ? 1.0f : 0.0f;
  o.y = (((double)p0.y + p1.y + p2.y + p3.y) > 0.5) ? 1.0f : 0.0f;
  o.z = (((double)p0.z + p1.z + p2.z + p3.z) > 0.5) ? 1.0f : 0.0f;
  o.w = (((double)p0.w + p1.w + p2.w + p3.w) > 0.5) ? 1.0f : 0.0f;
  *(f32x4*)(outg + e) = o;
}

extern "C" void kernel_launch(void* const* d_in, const int* in_sizes, int n_in,
                              void* d_out, int out_size, void* d_ws, size_t ws_size,
                              hipStream_t stream) {
  const float* x = (const float*)d_in[0];
  const float* a = (const float*)d_in[1];
  float* out = (float*)d_out;
  unsigned short* xs = (unsigned short*)d_ws;                 // 6 MB
  float* wp = (float*)((char*)d_ws + 3 * TOT * sizeof(unsigned short));

  prep_x<<<dim3(NROW / 64, BATCH), dim3(256), 0, stream>>>(x, xs);

  const size_t need = 3 * TOT * sizeof(unsigned short)
                    + (size_t)JSPLIT * TOT * sizeof(float);   // 22 MB
  if (ws_size >= need) {
    gemm_mfma<false><<<dim3(NROW / 64, JSPLIT, BATCH), dim3(256), 0, stream>>>(
        a, xs, out, wp);
    combine_thresh<<<dim3((unsigned)(TOT / 1024)), dim3(256), 0, stream>>>(wp, out);
  } else {
    gemm_mfma<true><<<dim3(NROW / 64, 1, BATCH), dim3(256), 0, stream>>>(
        a, xs, out, nullptr);
  }
}

// Round 7
// 47.846 us; speedup vs baseline: 2.4279x; 2.4279x over previous
//
#include <hip/hip_runtime.h>

#define BATCH 8
#define NROW  2048
#define NF    64
#define JSPLIT 4
#define JPB   (NROW / JSPLIT)               // 512 k per block (split path)
#define CHUNK 32
#define TOT   ((size_t)BATCH * NROW * NF)   // 1048576

typedef float  f32x4  __attribute__((ext_vector_type(4)));
typedef __bf16 bf16x8 __attribute__((ext_vector_type(8)));
typedef unsigned short u16x8 __attribute__((ext_vector_type(8)));

union frag_cast { u16x8 u; bf16x8 b; };

#define AS1 __attribute__((address_space(1)))
#define AS3 __attribute__((address_space(3)))

__device__ __forceinline__ void gld16f(const float* g, float* l) {
  __builtin_amdgcn_global_load_lds((const AS1 void*)g, (AS3 void*)l, 16, 0, 0);
}
__device__ __forceinline__ void gld16u(const unsigned short* g, unsigned short* l) {
  __builtin_amdgcn_global_load_lds((const AS1 void*)g, (AS3 void*)l, 16, 0, 0);
}
__device__ __forceinline__ float ubits(unsigned u) {
  union { unsigned u; float f; } c; c.u = u; return c.f;
}
__device__ __forceinline__ unsigned fbits(float f) {
  union { float f; unsigned u; } c; c.f = f; return c.u;
}

// ---- pass 1: transpose x, split into 3 bf16 levels: xs[lvl][b][f][j] ----
__global__ __launch_bounds__(256, 4)
void prep_x(const float* __restrict__ xg, unsigned short* __restrict__ xs) {
  __shared__ float t[64][65];
  const int b  = blockIdx.y;
  const int j0 = blockIdx.x * 64;
  const int l  = threadIdx.x & 63;
  const int g  = threadIdx.x >> 6;
  const float* src = xg + ((size_t)b * NROW + j0) * NF;
#pragma unroll
  for (int k = 0; k < 16; ++k) {
    const int j = g * 16 + k;
    t[j][l] = src[(size_t)j * NF + l];
  }
  __syncthreads();
#pragma unroll
  for (int k = 0; k < 16; ++k) {
    const int f = g * 16 + k;
    const float v = t[l][f];
    const unsigned u0 = fbits(v);
    const float f0 = ubits(u0 & 0xFFFF0000u);
    const float r  = v - f0;
    const unsigned u1 = fbits(r);
    const float f1 = ubits(u1 & 0xFFFF0000u);
    const float r2 = r - f1;
    const unsigned u2 = fbits(r2);
    const unsigned short s2 =
        (unsigned short)((u2 + 0x7FFFu + ((u2 >> 16) & 1u)) >> 16);
    const size_t o = ((size_t)b * NF + f) * NROW + j0 + l;
    xs[o]           = (unsigned short)(u0 >> 16);
    xs[o + TOT]     = (unsigned short)(u1 >> 16);
    xs[o + 2 * TOT] = s2;
  }
}

// split 8 f32 -> 3 bf16 fragments (proven r5/r6)
__device__ __forceinline__ void split8(const f32x4 q0, const f32x4 q1,
                                       frag_cast* Af) {
  float av[8];
  *(f32x4*)&av[0] = q0;
  *(f32x4*)&av[4] = q1;
  u16x8 h0, h1, h2;
#pragma unroll
  for (int e = 0; e < 8; ++e) {
    const unsigned u0 = fbits(av[e]);
    const float f0 = ubits(u0 & 0xFFFF0000u);
    const float r  = av[e] - f0;
    const unsigned u1 = fbits(r);
    const float f1 = ubits(u1 & 0xFFFF0000u);
    const float r2 = r - f1;
    const unsigned u2 = fbits(r2);
    h0[e] = (unsigned short)(u0 >> 16);
    h1[e] = (unsigned short)(u1 >> 16);
    h2[e] = (unsigned short)((u2 + 0x7FFFu + ((u2 >> 16) & 1u)) >> 16);
  }
  Af[0].u = h0; Af[1].u = h1; Af[2].u = h2;
}

// ---- pass 2: split-bf16 MFMA GEMM, A+B both LDS-staged (m97 shape) ----
// Block: 4 waves, tile 64 rows x 64 cols, K staged in 32-chunks.
// LDS/chunk: A 8KB f32 (XOR q^(row&7)) + B 12KB bf16x3lvl (XOR q^((n>>1)&3)),
// double-buffered = 40KB -> 4 blocks/CU. Staging = 5 global_load_lds/thread
// with pre-swizzled global source (linear LDS dest). One barrier per chunk.
// XCD-chunked block swizzle: batch b <-> XCD, so xs slice (768KB) L2-fits.
template <bool DIRECT>
__global__ __launch_bounds__(256, 4)
void gemm_mfma(const float* __restrict__ ag, const unsigned short* __restrict__ xs,
               float* __restrict__ outg, float* __restrict__ wp) {
  __shared__ __align__(16) float sA[2][64 * CHUNK];                 // 2 x 8KB
  __shared__ __align__(16) unsigned short sB[2][3 * 64 * CHUNK];    // 2 x 12KB

  const int tid  = threadIdx.x;
  const int ln   = tid & 63;
  const int wv   = tid >> 6;
  const int ln15 = ln & 15;          // A row / B col / D col
  const int g    = ln >> 4;          // k-group / D row-group
  const int akey = ln15 & 7;
  const int bkey = (ln15 >> 1) & 3;

  // XCD-chunked bijective swizzle of the flat block id (nwg % 8 == 0)
  const int nwg = gridDim.x * gridDim.y * gridDim.z;
  int flat = blockIdx.x + gridDim.x * (blockIdx.y + gridDim.y * blockIdx.z);
  flat = (flat & 7) * (nwg >> 3) + (flat >> 3);
  const int bx   = flat & 31;                     // gridDim.x == 32
  const int rest = flat >> 5;
  const int z    = DIRECT ? 0 : (rest & 3);
  const int b    = DIRECT ? rest : (rest >> 2);

  const int i0  = bx * 64;
  const int jb  = z * JPB;
  const int nch = (DIRECT ? NROW : JPB) / CHUNK;   // 64 or 16

  const float* aB = ag + ((size_t)b * NROW + i0) * NROW;
  const unsigned short* xB = xs + (size_t)b * NF * NROW;

  // stage chunk at k-offset j0 into buffer buf (linear dest, swizzled src)
  auto stage = [&](int buf, int j0) {
#pragma unroll
    for (int r = 0; r < 2; ++r) {            // A: 512 x 16B slots
      const int s   = r * 256 + tid;
      const int row = s >> 3;
      const int q   = (s & 7) ^ (row & 7);
      gld16f(aB + (size_t)row * NROW + j0 + q * 4,
             &sA[buf][0] + (r * 256 + wv * 64) * 4);
    }
#pragma unroll
    for (int lvl = 0; lvl < 3; ++lvl) {      // B: 3 x 256 x 16B slots
      const int n = tid >> 2;
      const int q = (tid & 3) ^ ((n >> 1) & 3);
      gld16u(xB + (size_t)lvl * TOT + (size_t)n * NROW + j0 + q * 8,
             &sB[buf][0] + (lvl * 256 + wv * 64) * 8);
    }
  };

  double macc[4][4];
#pragma unroll
  for (int i = 0; i < 4; ++i)
#pragma unroll
    for (int j = 0; j < 4; ++j) macc[i][j] = 0.0;

  constexpr int AI[6] = {2, 0, 1, 1, 0, 0};
  constexpr int BI[6] = {0, 2, 1, 0, 1, 0};

  stage(0, jb);

#pragma unroll 1
  for (int t = 0; t < nch; ++t) {
    __syncthreads();                  // drains stage(t); buf^1 free to overwrite
    if (t + 1 < nch) stage((t + 1) & 1, jb + (t + 1) * CHUNK);

    const float* sAb = &sA[t & 1][0];
    const unsigned short* sBb = &sB[t & 1][0];

    // A fragment: row wv*16+ln15, quads 2g, 2g+1 (unswizzle with akey)
    const int rowOff = (wv * 16 + ln15) * 32;
    const f32x4 q0 = *(const f32x4*)(sAb + rowOff + (((2 * g)     ^ akey) << 2));
    const f32x4 q1 = *(const f32x4*)(sAb + rowOff + (((2 * g + 1) ^ akey) << 2));
    frag_cast Af[3];
    split8(q0, q1, Af);

    const int bpos = (g ^ bkey) * 8;  // B quad position (u16 units)
    f32x4 c[4];
#pragma unroll
    for (int nt = 0; nt < 4; ++nt) c[nt] = (f32x4){0.f, 0.f, 0.f, 0.f};

#pragma unroll
    for (int ng = 0; ng < 2; ++ng) {
      frag_cast Bv[2][3];
#pragma unroll
      for (int nn = 0; nn < 2; ++nn)
#pragma unroll
        for (int lvl = 0; lvl < 3; ++lvl)
          Bv[nn][lvl].u = *(const u16x8*)(
              sBb + lvl * 2048 + ((ng * 2 + nn) * 16 + ln15) * 32 + bpos);
#pragma unroll
      for (int term = 0; term < 6; ++term)
#pragma unroll
        for (int nn = 0; nn < 2; ++nn) {
          const int nt = ng * 2 + nn;
          c[nt] = __builtin_amdgcn_mfma_f32_16x16x32_bf16(
              Af[AI[term]].b, Bv[nn][BI[term]].b, c[nt], 0, 0, 0);
        }
    }
#pragma unroll
    for (int nt = 0; nt < 4; ++nt) {
      macc[nt][0] += (double)c[nt].x;
      macc[nt][1] += (double)c[nt].y;
      macc[nt][2] += (double)c[nt].z;
      macc[nt][3] += (double)c[nt].w;
    }
  }

  // epilogue: D row = g*4 + r, col = nt*16 + ln15 (verified r5/r6)
  if (DIRECT) {
#pragma unroll
    for (int nt = 0; nt < 4; ++nt)
#pragma unroll
      for (int r = 0; r < 4; ++r)
        outg[((size_t)b * NROW + i0 + wv * 16 + g * 4 + r) * NF + nt * 16 + ln15] =
            (macc[nt][r] > 0.5) ? 1.0f : 0.0f;
  } else {
    float* wb = wp + (size_t)z * TOT;
#pragma unroll
    for (int nt = 0; nt < 4; ++nt)
#pragma unroll
      for (int r = 0; r < 4; ++r)
        wb[((size_t)b * NROW + i0 + wv * 16 + g * 4 + r) * NF + nt * 16 + ln15] =
            (float)macc[nt][r];
  }
}

// ---- pass 3: reduce JSPLIT partials in f64, threshold ----
__global__ __launch_bounds__(256)
void combine_thresh(const float* __restrict__ wsv, float* __restrict__ outg) {
  const size_t e = ((size_t)blockIdx.x * 256 + threadIdx.x) * 4;
  f32x4 p0 = *(const f32x4*)(wsv + e);
  f32x4 p1 = *(const f32x4*)(wsv + e + TOT);
  f32x4 p2 = *(const f32x4*)(wsv + e + 2 * TOT);
  f32x4 p3 = *(const f32x4*)(wsv + e + 3 * TOT);
  f32x4 o;
  o.x = (((double)p0.x + p1.x + p2.x + p3.x) > 0.5) ? 1.0f : 0.0f;
  o.y = (((double)p0.y + p1.y + p2.y + p3.y) > 0.5) ? 1.0f : 0.0f;
  o.z = (((double)p0.z + p1.z + p2.z + p3.z) > 0.5) ? 1.0f : 0.0f;
  o.w = (((double)p0.w + p1.w + p2.w + p3.w) > 0.5) ? 1.0f : 0.0f;
  *(f32x4*)(outg + e) = o;
}

extern "C" void kernel_launch(void* const* d_in, const int* in_sizes, int n_in,
                              void* d_out, int out_size, void* d_ws, size_t ws_size,
                              hipStream_t stream) {
  const float* x = (const float*)d_in[0];
  const float* a = (const float*)d_in[1];
  float* out = (float*)d_out;
  unsigned short* xs = (unsigned short*)d_ws;                 // 6 MB
  float* wp = (float*)((char*)d_ws + 3 * TOT * sizeof(unsigned short));

  prep_x<<<dim3(NROW / 64, BATCH), dim3(256), 0, stream>>>(x, xs);

  const size_t need = 3 * TOT * sizeof(unsigned short)
                    + (size_t)JSPLIT * TOT * sizeof(float);   // 22 MB
  if (ws_size >= need) {
    gemm_mfma<false><<<dim3(NROW / 64, JSPLIT, BATCH), dim3(256), 0, stream>>>(
        a, xs, out, wp);
    combine_thresh<<<dim3((unsigned)(TOT / 1024)), dim3(256), 0, stream>>>(wp, out);
  } else {
    gemm_mfma<true><<<dim3(NROW / 64, 1, BATCH), dim3(256), 0, stream>>>(
        a, xs, out, nullptr);
  }
}